// Round 11
// baseline (77.558 us; speedup 1.0000x reference)
//
#include <hip/hip_runtime.h>
#include <hip/hip_fp16.h>

#define BATCH 32
#define TLEN  4096
#define CH    128      // C == F == 128
#define KW    3
#define DIL   8

#define BM    64                 // output rows per block
#define HROWS (BM + 2 * DIL)     // 80  h rows
#define XROWS (BM + 4 * DIL)     // 96  x rows
#define LDSC  136                // 272B row stride: 16B-aligned, modest bank aliasing

typedef _Float16 f16x8 __attribute__((ext_vector_type(8)));
typedef float    f32x4 __attribute__((ext_vector_type(4)));

// ---------------------------------------------------------------------------
// LDS publish barrier without the vmcnt(0) drain __syncthreads() forces.
// ---------------------------------------------------------------------------
__device__ __forceinline__ void lds_publish_barrier() {
    __builtin_amdgcn_sched_barrier(0);
    asm volatile("s_waitcnt lgkmcnt(0)" ::: "memory");
    __builtin_amdgcn_s_barrier();
    __builtin_amdgcn_sched_barrier(0);
}

// ---------------------------------------------------------------------------
// Prep: Wt[j][f][c] = (f16) W[c][j][f]   for both layers' kernels.
// ---------------------------------------------------------------------------
__global__ void prep_weights_kernel(const float* __restrict__ W1,
                                    const float* __restrict__ W2,
                                    _Float16* __restrict__ Wt1,
                                    _Float16* __restrict__ Wt2) {
    const int total = KW * CH * CH;
    int idx = blockIdx.x * 256 + threadIdx.x;
    if (idx >= 2 * total) return;
    const float* W  = (idx < total) ? W1 : W2;
    _Float16*    Wt = (idx < total) ? Wt1 : Wt2;
    int r = idx % total;
    int j = r / (CH * CH);
    int f = (r / CH) % CH;
    int c = r % CH;
    Wt[j * CH * CH + f * CH + c] = (_Float16)W[c * (KW * CH) + j * CH + f];
}

// ---------------------------------------------------------------------------
// Fused TemporalDeConvBlock — OCCUPANCY build. The r8-r10 cycle model says
// LDS pipe ~45% busy is the top consumer and nothing else >20%: we are
// packing-limited at 8 waves/CU (2/SIMD, VGPR=220). This round trades the
// 96-VGPR weight-prefetch for in-loop L2 loads (#pragma unroll 1 stops the
// unroller from recreating the prefetch array) -> VGPR ~105 -> 4+ waves/SIMD
// and 4-6 co-resident blocks/CU whose phase diversity packs the LDS pipe.
// 256 thr = 4 waves; wave w owns cols [32w,32w+32) as two 16-col subtiles.
// Single aliased LDS buffer (26 KB): x window for G1, overwritten by h for
// G2; residual re-read from global (L3-resident). lgkm-only barriers.
// LESSONS: caps below live-set spill catastrophically (r3/r5); 512-thread
// blocks get pinned to 64 VGPR (r4/r6/r7); __syncthreads drains vmcnt (r9);
// per-wave ILP without TLP doesn't pack shared pipes (r9/r10).
// ---------------------------------------------------------------------------
__global__ __launch_bounds__(256, 4)   // cap 128 >> audited live ~105
void fused_deconv_kernel(const float* __restrict__ x,
                         const _Float16* __restrict__ Wt1,
                         const float* __restrict__ bias1,
                         const _Float16* __restrict__ Wt2,
                         const float* __restrict__ bias2,
                         float* __restrict__ out)
{
    __shared__ __align__(16) _Float16 buf[XROWS][LDSC];   // 96*272 = 26112 B

    const int tid  = threadIdx.x;
    const int lane = tid & 63;
    const int wid  = tid >> 6;         // 0..3
    const int l15  = lane & 15;
    const int kg   = lane >> 4;        // 0..3
    const int nc   = wid << 5;         // wave column base: 0,32,64,96

    const int bt = blockIdx.x;
    const int b  = bt >> 6;            // 64 tiles per batch
    const int t0 = (bt & 63) << 6;

    // ---- stage x window (f32 -> f16), rows t0..t0+95, zero past TLEN
#pragma unroll
    for (int p = 0; p < 6; ++p) {
        const int i   = tid + 256 * p;
        const int row = i >> 4;
        const int c8  = (i & 15) << 3;
        const int t   = t0 + row;
        f16x8 o;
        if (t < TLEN) {
            const float* xp = x + ((size_t)b * TLEN + t) * CH + c8;
            f32x4 v0 = *(const f32x4*)(xp + 0);
            f32x4 v1 = *(const f32x4*)(xp + 4);
            o[0] = (_Float16)v0[0]; o[1] = (_Float16)v0[1];
            o[2] = (_Float16)v0[2]; o[3] = (_Float16)v0[3];
            o[4] = (_Float16)v1[0]; o[5] = (_Float16)v1[1];
            o[6] = (_Float16)v1[2]; o[7] = (_Float16)v1[3];
        } else {
            o = (f16x8){};
        }
        *(f16x8*)&buf[row][c8] = o;
    }

    const float bv1_0 = 128.0f * bias1[nc + l15];
    const float bv1_1 = 128.0f * bias1[nc + 16 + l15];
    const float bv2_0 = 128.0f * bias2[nc + l15];
    const float bv2_1 = 128.0f * bias2[nc + 16 + l15];

    lds_publish_barrier();

    // ---- GEMM1: h rows 0..79, cols [nc,nc+32). W1 frags loaded in-loop
    // from L2 (hot, 96 KB); latency hidden by TLP (16-24 waves/CU).
    f32x4 acc1[5][2];
#pragma unroll
    for (int m = 0; m < 5; ++m) {
        acc1[m][0] = (f32x4){0.f, 0.f, 0.f, 0.f};
        acc1[m][1] = (f32x4){0.f, 0.f, 0.f, 0.f};
    }
    {
        const _Float16* wb = Wt1 + (nc + l15) * CH + kg * 8;
#pragma unroll 1
        for (int ks = 0; ks < 12; ++ks) {
            const int j     = ks >> 2;
            const int c0    = (ks & 3) << 5;
            const int shift = (2 - j) << 3;
            const _Float16* wp = wb + j * (CH * CH) + c0;
            f16x8 w0 = *(const f16x8*)(wp);
            f16x8 w1 = *(const f16x8*)(wp + 16 * CH);
#pragma unroll
            for (int m = 0; m < 5; ++m) {
                f16x8 af = *(const f16x8*)&buf[m * 16 + shift + l15][c0 + kg * 8];
                acc1[m][0] = __builtin_amdgcn_mfma_f32_16x16x32_f16(af, w0, acc1[m][0], 0, 0, 0);
                acc1[m][1] = __builtin_amdgcn_mfma_f32_16x16x32_f16(af, w1, acc1[m][1], 0, 0, 0);
            }
        }
    }

    lds_publish_barrier();   // all G1 x-reads complete before h overwrites

    // ---- h-store into the SAME buffer (relu + bias; rows past TLEN zero)
#pragma unroll
    for (int m = 0; m < 5; ++m) {
#pragma unroll
        for (int nn = 0; nn < 2; ++nn) {
            const float bv = nn ? bv1_1 : bv1_0;
            const int f = nc + nn * 16 + l15;
#pragma unroll
            for (int i = 0; i < 4; ++i) {
                const int r = m * 16 + kg * 4 + i;
                const int u = t0 + r;
                const int nv = 1 + (u < TLEN - DIL) + (u < TLEN - 2 * DIL);
                float v = acc1[m][nn][i] + (float)nv * bv;
                v = fmaxf(v, 0.0f);
                buf[r][f] = (u < TLEN) ? (_Float16)v : (_Float16)0.0f;
            }
        }
    }

    lds_publish_barrier();   // h visible

    // ---- residual: issue early (retires under G2)
    float rx[4][2][4];
#pragma unroll
    for (int m = 0; m < 4; ++m)
#pragma unroll
        for (int nn = 0; nn < 2; ++nn) {
            const int f = nc + nn * 16 + l15;
#pragma unroll
            for (int i = 0; i < 4; ++i) {
                const int r = m * 16 + kg * 4 + i;
                rx[m][nn][i] = x[((size_t)b * TLEN + t0 + r) * CH + f];
            }
        }

    // ---- GEMM2: out rows 0..63, cols [nc,nc+32). W2 frags in-loop.
    f32x4 acc2[4][2];
#pragma unroll
    for (int m = 0; m < 4; ++m) {
        acc2[m][0] = (f32x4){0.f, 0.f, 0.f, 0.f};
        acc2[m][1] = (f32x4){0.f, 0.f, 0.f, 0.f};
    }
    {
        const _Float16* wb = Wt2 + (nc + l15) * CH + kg * 8;
#pragma unroll 1
        for (int ks = 0; ks < 12; ++ks) {
            const int j     = ks >> 2;
            const int c0    = (ks & 3) << 5;
            const int shift = (2 - j) << 3;
            const _Float16* wp = wb + j * (CH * CH) + c0;
            f16x8 w0 = *(const f16x8*)(wp);
            f16x8 w1 = *(const f16x8*)(wp + 16 * CH);
#pragma unroll
            for (int m = 0; m < 4; ++m) {
                f16x8 af = *(const f16x8*)&buf[m * 16 + shift + l15][c0 + kg * 8];
                acc2[m][0] = __builtin_amdgcn_mfma_f32_16x16x32_f16(af, w0, acc2[m][0], 0, 0, 0);
                acc2[m][1] = __builtin_amdgcn_mfma_f32_16x16x32_f16(af, w1, acc2[m][1], 0, 0, 0);
            }
        }
    }

    // ---- epilogue: bias2 + relu, + residual, relu, store f32
#pragma unroll
    for (int m = 0; m < 4; ++m) {
#pragma unroll
        for (int nn = 0; nn < 2; ++nn) {
            const float bv = nn ? bv2_1 : bv2_0;
            const int f = nc + nn * 16 + l15;
#pragma unroll
            for (int i = 0; i < 4; ++i) {
                const int r = m * 16 + kg * 4 + i;
                const int t = t0 + r;
                const int nv = 1 + (t < TLEN - DIL) + (t < TLEN - 2 * DIL);
                float v = acc2[m][nn][i] + (float)nv * bv;
                v = fmaxf(v, 0.0f);
                v = fmaxf(v + rx[m][nn][i], 0.0f);
                out[((size_t)b * TLEN + t) * CH + f] = v;
            }
        }
    }
}

// ---------------------------------------------------------------------------
extern "C" void kernel_launch(void* const* d_in, const int* in_sizes, int n_in,
                              void* d_out, int out_size, void* d_ws, size_t ws_size,
                              hipStream_t stream) {
    const float* x  = (const float*)d_in[0];
    const float* W1 = (const float*)d_in[1];
    const float* b1 = (const float*)d_in[2];
    const float* W2 = (const float*)d_in[3];
    const float* b2 = (const float*)d_in[4];
    float* out = (float*)d_out;

    _Float16* Wt1 = (_Float16*)d_ws;
    _Float16* Wt2 = Wt1 + KW * CH * CH;

    prep_weights_kernel<<<(2 * KW * CH * CH + 255) / 256, 256, 0, stream>>>(W1, W2, Wt1, Wt2);

    const int grid = BATCH * (TLEN / BM);   // 2048 blocks
    fused_deconv_kernel<<<grid, 256, 0, stream>>>(x, Wt1, b1, Wt2, b2, out);
}

// Round 12
// 67.193 us; speedup vs baseline: 1.1543x; 1.1543x over previous
//
#include <hip/hip_runtime.h>
#include <hip/hip_fp16.h>

#define BATCH 32
#define TLEN  4096
#define CH    128      // C == F == 128
#define KW    3
#define DIL   8

#define BM    128                // output rows per block
#define HR    (BM + 2 * DIL)     // 144  h rows needed
#define WROWS (BM + 4 * DIL)     // 160  x rows needed
#define LDSC  132                // 264B stride = 66 dwords ≡ 2 (mod 32):
                                 // A-frag b128 reads ~2-way bank alias (FREE, m136).
                                 // 136 (68≡4 mod 32) gave 8-way conflicts: the
                                 // r6-r11 SQ_LDS_BANK_CONFLICT 7-9x jump. DO NOT
                                 // use stride ≡ 0/4 mod 32 dwords.

typedef _Float16 f16x8 __attribute__((ext_vector_type(8)));
typedef float    f32x4 __attribute__((ext_vector_type(4)));

// ---------------------------------------------------------------------------
// Prep: Wt[j][f][c] = (f16) W[c][j][f]   for both layers' kernels.
// W is (C, K, F) row-major: W[c*KW*CH + j*CH + f].
// ---------------------------------------------------------------------------
__global__ void prep_weights_kernel(const float* __restrict__ W1,
                                    const float* __restrict__ W2,
                                    _Float16* __restrict__ Wt1,
                                    _Float16* __restrict__ Wt2) {
    const int total = KW * CH * CH;
    int idx = blockIdx.x * 256 + threadIdx.x;
    if (idx >= 2 * total) return;
    const float* W  = (idx < total) ? W1 : W2;
    _Float16*    Wt = (idx < total) ? Wt1 : Wt2;
    int r = idx % total;
    int j = r / (CH * CH);
    int f = (r / CH) % CH;
    int c = r % CH;
    Wt[j * CH * CH + f * CH + c] = (_Float16)W[c * (KW * CH) + j * CH + f];
}

// ---------------------------------------------------------------------------
// Fused TemporalDeConvBlock. 256 threads = 4 waves; wave w owns cols
// [32w, 32w+32) as TWO 16-col sub-tiles (each A ds_read feeds 2 MFMA).
// BM=128: one 160-row x window staged once; h (144 rows) overwrites the
// dead x window; residual re-read from global x (L2/L3-resident).
// This is the r8 kernel (best measured, 70.3us, VGPR=176 no spill) with:
//   * LDSC 136 -> 132 (kills the 8-way A-read bank conflict, see above)
//   * XCD-aware bijective block swizzle (adjacent tiles share 20% halo +
//     all weights -> same-XCD L2 locality; grid 1024 % 8 == 0)
// VGPR: 256-thread block, NO waves-per-EU bound (cap 256); peak live ~190.
// LESSONS: caps below live-set spill catastrophically (r3/r5); 512-thread
// blocks are pinned to 64 VGPR regardless of bounds (r4/r6/r7); occupancy
// 10% vs 39% gives identical perf (r8 vs r11) -> TLP is not the limiter.
// ---------------------------------------------------------------------------
__global__ __launch_bounds__(256)
void fused_deconv_kernel(const float* __restrict__ x,
                         const _Float16* __restrict__ Wt1,
                         const float* __restrict__ bias1,
                         const _Float16* __restrict__ Wt2,
                         const float* __restrict__ bias2,
                         float* __restrict__ out)
{
    __shared__ __align__(16) _Float16 buf[WROWS][LDSC];   // 160*264 = 42240 B

    const int tid  = threadIdx.x;
    const int lane = tid & 63;
    const int wid  = tid >> 6;         // 0..3
    const int l15  = lane & 15;
    const int kg   = lane >> 4;        // 0..3
    const int nc   = wid << 5;         // wave column base: 0,32,64,96

    // XCD-aware bijective swizzle: grid = 1024 = 8 XCDs x 128 chunks.
    // Consecutive post-swizzle tiles (halo + weight sharing) land on the
    // same XCD's L2.
    const int bt0 = blockIdx.x;
    const int bt  = (bt0 & 7) * 128 + (bt0 >> 3);

    const int b  = bt >> 5;            // TLEN/BM = 32 tiles per batch
    const int t0 = (bt & 31) << 7;

    // ---- prefetch GEMM1 weight fragments (24 x 16B = 96 VGPRs); L2 latency
    // overlaps the x staging below.
    f16x8 w1[12][2];
#pragma unroll
    for (int ks = 0; ks < 12; ++ks) {
        const int j  = ks >> 2;
        const int c0 = (ks & 3) << 5;
        const _Float16* wb = Wt1 + (size_t)j * (CH * CH) + c0 + kg * 8;
        w1[ks][0] = *(const f16x8*)(wb + (nc + l15) * CH);
        w1[ks][1] = *(const f16x8*)(wb + (nc + 16 + l15) * CH);
    }

    // ---- stage x window (f32 -> f16), rows t0..t0+159, zero past TLEN.
#pragma unroll
    for (int p = 0; p < 10; ++p) {
        const int i   = tid + 256 * p;
        const int row = i >> 4;
        const int c8  = (i & 15) << 3;
        const int t   = t0 + row;
        f16x8 o;
        if (t < TLEN) {
            const float* xp = x + ((size_t)b * TLEN + t) * CH + c8;
            f32x4 v0 = *(const f32x4*)(xp + 0);
            f32x4 v1 = *(const f32x4*)(xp + 4);
            o[0] = (_Float16)v0[0]; o[1] = (_Float16)v0[1];
            o[2] = (_Float16)v0[2]; o[3] = (_Float16)v0[3];
            o[4] = (_Float16)v1[0]; o[5] = (_Float16)v1[1];
            o[6] = (_Float16)v1[2]; o[7] = (_Float16)v1[3];
        } else {
            o = (f16x8){};
        }
        *(f16x8*)&buf[row][c8] = o;
    }

    const float bv1_0 = 128.0f * bias1[nc + l15];
    const float bv1_1 = 128.0f * bias1[nc + 16 + l15];
    const float bv2_0 = 128.0f * bias2[nc + l15];
    const float bv2_1 = 128.0f * bias2[nc + 16 + l15];

    __syncthreads();

    // ---- GEMM1: h rows 0..143, cols [nc,nc+32) — 216 MFMA / 108 ds_read
    f32x4 acc1[9][2];
#pragma unroll
    for (int m = 0; m < 9; ++m) {
        acc1[m][0] = (f32x4){0.f, 0.f, 0.f, 0.f};
        acc1[m][1] = (f32x4){0.f, 0.f, 0.f, 0.f};
    }
#pragma unroll
    for (int ks = 0; ks < 12; ++ks) {
        const int j     = ks >> 2;
        const int c0    = (ks & 3) << 5;
        const int shift = (2 - j) * DIL;
#pragma unroll
        for (int m = 0; m < 9; ++m) {
            f16x8 af = *(const f16x8*)&buf[m * 16 + shift + l15][c0 + kg * 8];
            acc1[m][0] = __builtin_amdgcn_mfma_f32_16x16x32_f16(af, w1[ks][0], acc1[m][0], 0, 0, 0);
            acc1[m][1] = __builtin_amdgcn_mfma_f32_16x16x32_f16(af, w1[ks][1], acc1[m][1], 0, 0, 0);
        }
    }

    // ---- prefetch GEMM2 weights (w1 dead, regs recycle); latency hides
    // under the barrier + h-store below.
    f16x8 w2[12][2];
#pragma unroll
    for (int ks = 0; ks < 12; ++ks) {
        const int j  = ks >> 2;
        const int c0 = (ks & 3) << 5;
        const _Float16* wb = Wt2 + (size_t)j * (CH * CH) + c0 + kg * 8;
        w2[ks][0] = *(const f16x8*)(wb + (nc + l15) * CH);
        w2[ks][1] = *(const f16x8*)(wb + (nc + 16 + l15) * CH);
    }

    // all waves done READING the x window before h overwrites it
    __syncthreads();

    // ---- store h rows 0..143 into the SAME buffer (relu + bias)
#pragma unroll
    for (int m = 0; m < 9; ++m) {
#pragma unroll
        for (int nn = 0; nn < 2; ++nn) {
            const float bv = nn ? bv1_1 : bv1_0;
            const int f = nc + nn * 16 + l15;
#pragma unroll
            for (int i = 0; i < 4; ++i) {
                const int r = m * 16 + kg * 4 + i;
                const int u = t0 + r;
                const int nv = 1 + (u < TLEN - DIL) + (u < TLEN - 2 * DIL);
                float v = acc1[m][nn][i] + (float)nv * bv;
                v = fmaxf(v, 0.0f);
                buf[r][f] = (u < TLEN) ? (_Float16)v : (_Float16)0.0f;
            }
        }
    }
    __syncthreads();

    // ---- GEMM2: out rows 0..127, cols [nc,nc+32) — 192 MFMA / 96 ds_read
    f32x4 acc2[8][2];
#pragma unroll
    for (int m = 0; m < 8; ++m) {
        acc2[m][0] = (f32x4){0.f, 0.f, 0.f, 0.f};
        acc2[m][1] = (f32x4){0.f, 0.f, 0.f, 0.f};
    }
#pragma unroll
    for (int ks = 0; ks < 12; ++ks) {
        const int j     = ks >> 2;
        const int c0    = (ks & 3) << 5;
        const int shift = (2 - j) * DIL;
#pragma unroll
        for (int m = 0; m < 8; ++m) {
            f16x8 af = *(const f16x8*)&buf[m * 16 + shift + l15][c0 + kg * 8];
            acc2[m][0] = __builtin_amdgcn_mfma_f32_16x16x32_f16(af, w2[ks][0], acc2[m][0], 0, 0, 0);
            acc2[m][1] = __builtin_amdgcn_mfma_f32_16x16x32_f16(af, w2[ks][1], acc2[m][1], 0, 0, 0);
        }
    }

    // ---- epilogue: bias2 + relu, + residual (f32 x from global), relu, store
#pragma unroll
    for (int m = 0; m < 8; ++m) {
#pragma unroll
        for (int nn = 0; nn < 2; ++nn) {
            const float bv = nn ? bv2_1 : bv2_0;
            const int f = nc + nn * 16 + l15;
#pragma unroll
            for (int i = 0; i < 4; ++i) {
                const int r = m * 16 + kg * 4 + i;
                const int t = t0 + r;
                const int nv = 1 + (t < TLEN - DIL) + (t < TLEN - 2 * DIL);
                float v = acc2[m][nn][i] + (float)nv * bv;
                v = fmaxf(v, 0.0f);
                const size_t gi = ((size_t)b * TLEN + t) * CH + f;
                v = v + x[gi];
                v = fmaxf(v, 0.0f);
                out[gi] = v;
            }
        }
    }
}

// ---------------------------------------------------------------------------
extern "C" void kernel_launch(void* const* d_in, const int* in_sizes, int n_in,
                              void* d_out, int out_size, void* d_ws, size_t ws_size,
                              hipStream_t stream) {
    const float* x  = (const float*)d_in[0];
    const float* W1 = (const float*)d_in[1];
    const float* b1 = (const float*)d_in[2];
    const float* W2 = (const float*)d_in[3];
    const float* b2 = (const float*)d_in[4];
    float* out = (float*)d_out;

    _Float16* Wt1 = (_Float16*)d_ws;
    _Float16* Wt2 = Wt1 + KW * CH * CH;

    prep_weights_kernel<<<(2 * KW * CH * CH + 255) / 256, 256, 0, stream>>>(W1, W2, Wt1, Wt2);

    const int grid = BATCH * (TLEN / BM);   // 1024 blocks (= 8 XCDs x 128)
    fused_deconv_kernel<<<grid, 256, 0, stream>>>(x, Wt1, b1, Wt2, b2, out);
}